// Round 5
// baseline (540.958 us; speedup 1.0000x reference)
//
#include <hip/hip_runtime.h>
#include <hip/hip_cooperative_groups.h>
#include <math.h>

namespace cg = cooperative_groups;

#define LLEN 4096
#define CCH 128
#define DI 384
#define NST 4
#define SBN 6        // 3 directions x B=2
#define NB 2
#define FCH 512
#define NCHUNK 128
#define TSTEP 32

typedef short bf16x8 __attribute__((ext_vector_type(8)));
typedef short bf16x4 __attribute__((ext_vector_type(4)));
typedef float f32x4 __attribute__((ext_vector_type(4)));
typedef float f32x8 __attribute__((ext_vector_type(8)));

__device__ __forceinline__ float wave_sum(float v) {
#pragma unroll
    for (int o = 32; o > 0; o >>= 1) v += __shfl_xor(v, o);
    return v;
}

__device__ __forceinline__ short f2bf(float f) {
    unsigned int u = __float_as_uint(f);
    unsigned int r = (u + 0x7fffu + ((u >> 16) & 1u)) >> 16;
    return (short)r;
}
__device__ __forceinline__ float bf2f(short s) {
    return __uint_as_float(((unsigned int)(unsigned short)s) << 16);
}

// ---------------- weight bf16 pool offsets (elements) ----------------
#define OFF_IN  0         // in_w                 768x128
#define OFF_DTC 98304     // composed dt_w@xp_w[:128]  384x384 (rows 0..383)
#define OFF_BC  245760    //   + xp_w rows 128..135 as rows 384..391 (same ld=384)
#define OFF_OUT 248832    // out_w                128x384
#define OFF_FC1 297984    // fc1_w                512x128
#define OFF_FC2 363520    // fc2_w                128x512
#define OFF_END 429056
#define NCONV   281600    // convertible elements (everything except DTC region)
#define NCBLK   1100      // ceil(281600/256)

// merged: plain conversions + dt_w@xp_w composition
__global__ __launch_bounds__(256) void conv_comp(const float* __restrict__ in_w,
                                                 const float* __restrict__ xp_w,
                                                 const float* __restrict__ dt_w,
                                                 const float* __restrict__ out_w,
                                                 const float* __restrict__ fc1_w,
                                                 const float* __restrict__ fc2_w,
                                                 short* __restrict__ wb)
{
    int bid = blockIdx.x;
    if (bid < NCBLK) {
        int i = bid * 256 + threadIdx.x;
        if (i >= NCONV) return;
        int idx = (i < OFF_DTC) ? i : i + (OFF_OUT - OFF_DTC);  // skip composed region
        float v;
        if (idx < OFF_DTC)      v = in_w[idx];
        else if (idx < OFF_OUT) v = xp_w[128 * 384 + (idx - OFF_BC)];   // bc rows
        else if (idx < OFF_FC1) v = out_w[idx - OFF_OUT];
        else if (idx < OFF_FC2) v = fc1_w[idx - OFF_FC1];
        else                    v = fc2_w[idx - OFF_FC2];
        wb[idx] = f2bf(v);
    } else {
        int ji = (bid - NCBLK) * 256 + threadIdx.x;   // 0 .. 147455
        int j = ji / 384, k = ji % 384;
        float acc = 0.f;
#pragma unroll 8
        for (int n = 0; n < 128; n++)
            acc += dt_w[j * 128 + n] * xp_w[n * 384 + k];
        wb[OFF_DTC + j * 384 + k] = f2bf(acc);
    }
}

// ---------------- LayerNorm over C=128, building x_in on the fly (4 rows/block) ----------------
__global__ __launch_bounds__(256) void prep_ln1(const float* __restrict__ x,
                                                const int* __restrict__ ridx,
                                                const float* __restrict__ g,
                                                const float* __restrict__ b,
                                                short* __restrict__ xn)
{
    int r = blockIdx.x * 4 + (threadIdx.x >> 6);
    int lane = threadIdx.x & 63;
    int sb = r / LLEN, l = r % LLEN;
    int s = sb >> 1, bb = sb & 1;
    int srcl = (s == 0) ? l : (s == 1 ? (LLEN - 1 - l) : ridx[l]);
    const float* src = x + ((size_t)bb * LLEN + srcl) * CCH;
    float v0 = src[lane], v1 = src[lane + 64];
    float m = wave_sum(v0 + v1) * (1.f / 128.f);
    float d0 = v0 - m, d1 = v1 - m;
    float var = wave_sum(d0 * d0 + d1 * d1) * (1.f / 128.f);
    float rstd = rsqrtf(var + 1e-5f);
    short* dst = xn + (size_t)r * CCH;
    dst[lane]      = f2bf(d0 * rstd * g[lane]      + b[lane]);
    dst[lane + 64] = f2bf(d1 * rstd * g[lane + 64] + b[lane + 64]);
}

// ---------------- wide MFMA GEMM (64x128 tile) ----------------
// EPI: 3=bias+residual f32   5=bf16   6=bias bf16
//      7=dtc+bc split: col<384 bias+softplus bf16 -> Cb; col 384..391 f32 -> extra
//      8=f32 out + per-column block sums atomically added to extra (means)
template<int EPI>
__global__ __launch_bounds__(256) void gemm_w(const short* __restrict__ A, int lda,
                                              const short* __restrict__ W, int ldw, int Ntot,
                                              const float* __restrict__ bias,
                                              const float* __restrict__ res, int ldr,
                                              float* __restrict__ C0,
                                              short* __restrict__ Cb, int ldc,
                                              float* __restrict__ extra,
                                              int Kd)
{
    __shared__ short Als[64 * 72];
    __shared__ short Wls[128 * 72];
    int tid = threadIdx.x;
    int wid = tid >> 6, lane = tid & 63;
    int wm = wid >> 1, wn = wid & 1;
    int l15 = lane & 15, l4 = lane >> 4;
    int bm = blockIdx.x * 64, bn = blockIdx.y * 128;
    int srow = tid >> 3, scol = (tid & 7) * 8;
    f32x4 acc[2][4] = {};
    for (int k0 = 0; k0 < Kd; k0 += 64) {
        bf16x8 av0 = *(const bf16x8*)&A[(size_t)(bm + srow) * lda + k0 + scol];
        bf16x8 av1 = *(const bf16x8*)&A[(size_t)(bm + srow + 32) * lda + k0 + scol];
        bf16x8 wv[4];
#pragma unroll
        for (int q = 0; q < 4; q++) {
            if (EPI == 7) {
                wv[q] = bf16x8{};
                if (bn + srow + 32 * q < Ntot)
                    wv[q] = *(const bf16x8*)&W[(size_t)(bn + srow + 32 * q) * ldw + k0 + scol];
            } else {
                wv[q] = *(const bf16x8*)&W[(size_t)(bn + srow + 32 * q) * ldw + k0 + scol];
            }
        }
        __syncthreads();
        *(bf16x8*)&Als[srow * 72 + scol] = av0;
        *(bf16x8*)&Als[(srow + 32) * 72 + scol] = av1;
#pragma unroll
        for (int q = 0; q < 4; q++)
            *(bf16x8*)&Wls[(srow + 32 * q) * 72 + scol] = wv[q];
        __syncthreads();
#pragma unroll
        for (int ks = 0; ks < 2; ks++) {
            bf16x8 af[2], bw[4];
#pragma unroll
            for (int f = 0; f < 2; f++)
                af[f] = *(const bf16x8*)&Als[(wm * 32 + f * 16 + l15) * 72 + ks * 32 + l4 * 8];
#pragma unroll
            for (int j = 0; j < 4; j++)
                bw[j] = *(const bf16x8*)&Wls[(wn * 64 + j * 16 + l15) * 72 + ks * 32 + l4 * 8];
#pragma unroll
            for (int i = 0; i < 2; i++)
#pragma unroll
                for (int j = 0; j < 4; j++)
                    acc[i][j] = __builtin_amdgcn_mfma_f32_16x16x32_bf16(af[i], bw[j], acc[i][j], 0, 0, 0);
        }
    }
    __shared__ float cs[128];
    if (EPI == 8) {
        if (tid < 128) cs[tid] = 0.f;
        __syncthreads();
    }
#pragma unroll
    for (int i = 0; i < 2; i++) {
        int row0 = bm + wm * 32 + i * 16 + l4 * 4;
#pragma unroll
        for (int j = 0; j < 4; j++) {
            int col = bn + wn * 64 + j * 16 + l15;
            if (EPI == 7) {
                if (col < 384) {
                    float bv = bias[col];
#pragma unroll
                    for (int r = 0; r < 4; r++) {
                        float v = acc[i][j][r] + bv;
                        v = (v > 20.f) ? v : __logf(1.f + __expf(v));
                        Cb[(size_t)(row0 + r) * ldc + col] = f2bf(v);
                    }
                } else if (col < 392) {
#pragma unroll
                    for (int r = 0; r < 4; r++)
                        extra[(size_t)(row0 + r) * 8 + (col - 384)] = acc[i][j][r];
                }
            } else {
                float bv = (EPI == 3 || EPI == 6) ? bias[col] : 0.f;
                float csum = 0.f;
#pragma unroll
                for (int r = 0; r < 4; r++) {
                    float v = acc[i][j][r] + bv;
                    if (EPI == 3) v += res[(size_t)(row0 + r) * ldr + col];
                    if (EPI == 5 || EPI == 6)
                        Cb[(size_t)(row0 + r) * ldc + col] = f2bf(v);
                    else
                        C0[(size_t)(row0 + r) * ldc + col] = v;
                    csum += v;
                }
                if (EPI == 8) atomicAdd(&cs[wn * 64 + j * 16 + l15], csum);
            }
        }
    }
    if (EPI == 8) {
        __syncthreads();
        if (tid < 128) atomicAdd(&extra[(bm >> 12) * 128 + tid], cs[tid]);
    }
}

// ---------------- depthwise causal conv K=4 + bias + SiLU: sliding-window vectorized ----------------
__global__ __launch_bounds__(192) void dwconv_silu_v2(const short* __restrict__ hg,
                                                      const float* __restrict__ cw,
                                                      const float* __restrict__ cb,
                                                      short* __restrict__ ub)
{
    int t = threadIdx.x;
    int c = t % 48, rs = t / 48;
    int blk = blockIdx.x;            // 768 blocks: 6 sb x 128
    int sb = blk >> 7;
    int l0 = ((blk & 127) << 5) + rs * 8;
    int d0 = c * 8;
    float w0[8], w1[8], w2[8], w3[8], bs[8];
#pragma unroll
    for (int e = 0; e < 8; e++) {
        int d = d0 + e;
        bs[e] = cb[d];
        w0[e] = cw[d * 4 + 0]; w1[e] = cw[d * 4 + 1];
        w2[e] = cw[d * 4 + 2]; w3[e] = cw[d * 4 + 3];
    }
    float r0[8], r1[8], r2[8];
#pragma unroll
    for (int e = 0; e < 8; e++) { r0[e] = 0.f; r1[e] = 0.f; r2[e] = 0.f; }
    if (l0 - 3 >= 0) { bf16x8 v = *(const bf16x8*)&hg[(size_t)(sb * LLEN + l0 - 3) * 768 + d0];
#pragma unroll
        for (int e = 0; e < 8; e++) r0[e] = bf2f(v[e]); }
    if (l0 - 2 >= 0) { bf16x8 v = *(const bf16x8*)&hg[(size_t)(sb * LLEN + l0 - 2) * 768 + d0];
#pragma unroll
        for (int e = 0; e < 8; e++) r1[e] = bf2f(v[e]); }
    if (l0 - 1 >= 0) { bf16x8 v = *(const bf16x8*)&hg[(size_t)(sb * LLEN + l0 - 1) * 768 + d0];
#pragma unroll
        for (int e = 0; e < 8; e++) r2[e] = bf2f(v[e]); }
#pragma unroll
    for (int i = 0; i < 8; i++) {
        int row = sb * LLEN + l0 + i;
        bf16x8 v = *(const bf16x8*)&hg[(size_t)row * 768 + d0];
        float r3[8];
#pragma unroll
        for (int e = 0; e < 8; e++) r3[e] = bf2f(v[e]);
        bf16x8 ov;
#pragma unroll
        for (int e = 0; e < 8; e++) {
            float a = bs[e] + w0[e] * r0[e] + w1[e] * r1[e] + w2[e] * r2[e] + w3[e] * r3[e];
            ov[e] = f2bf(a * __builtin_amdgcn_rcpf(1.f + __expf(-a)));
        }
        *(bf16x8*)&ub[(size_t)row * DI + d0] = ov;
#pragma unroll
        for (int e = 0; e < 8; e++) { r0[e] = r1[e]; r1[e] = r2[e]; r2[e] = r3[e]; }
    }
}

// ---------------- cooperative fused selective scan (A + lookback + C in one launch) ----------------
__global__ __launch_bounds__(DI, 5) void scan_fused(const short* __restrict__ dtb,
                                                    const float* __restrict__ bc,
                                                    const short* __restrict__ ub,
                                                    const short* __restrict__ hg,
                                                    const float* __restrict__ A_log,
                                                    const float* __restrict__ Dp,
                                                    float* __restrict__ PS,
                                                    float* __restrict__ I,
                                                    short* __restrict__ ymix)
{
    __shared__ short ds_dt[TSTEP * DI];
    __shared__ short ds_u[TSTEP * DI];
    __shared__ float ds_bc[TSTEP * 8];
    int tid = threadIdx.x;
    int bid = blockIdx.x;
    int sb = bid / NCHUNK, chunk = bid % NCHUNK;
    int base = sb * LLEN + chunk * TSTEP;
    // ---- stage dt, u, bc into LDS (vectorized) ----
    {
        int rr = tid / 48, cc = (tid % 48) * 8;
#pragma unroll
        for (int p = 0; p < 4; p++) {
            int row = p * 8 + rr;
            *(bf16x8*)&ds_dt[row * DI + cc] = *(const bf16x8*)&dtb[(size_t)(base + row) * DI + cc];
            *(bf16x8*)&ds_u[row * DI + cc]  = *(const bf16x8*)&ub[(size_t)(base + row) * DI + cc];
        }
        if (tid < TSTEP * 8) ds_bc[tid] = bc[(size_t)base * 8 + tid];
    }
    int d = tid;
    f32x4 al = *(const f32x4*)&A_log[d * 4];
    float a[NST];
#pragma unroll
    for (int n = 0; n < NST; n++) a[n] = -__expf(al[n]);
    __syncthreads();
    // ---- phase A: per-chunk zero-init scan ----
    float s[NST] = {0.f, 0.f, 0.f, 0.f}, p[NST] = {1.f, 1.f, 1.f, 1.f};
    for (int t = 0; t < TSTEP; t++) {
        float dtv = bf2f(ds_dt[t * DI + d]);
        float dtu = dtv * bf2f(ds_u[t * DI + d]);
#pragma unroll
        for (int n = 0; n < NST; n++) {
            float dA = __expf(dtv * a[n]);
            s[n] = dA * s[n] + dtu * ds_bc[t * 8 + n];
            p[n] *= dA;
        }
    }
    {
        f32x8 v;
#pragma unroll
        for (int n = 0; n < NST; n++) { v[2 * n] = p[n]; v[2 * n + 1] = s[n]; }
        *(f32x8*)&PS[(size_t)(sb * NCHUNK + chunk) * 3072 + d * 8] = v;
    }
    __threadfence();
    cg::this_grid().sync();
    // ---- phase B: cross-chunk prefix (24 blocks, prefetch-8) ----
    if (bid < 24) {
        int sb2 = bid >> 2;
        int dn = (bid & 3) * 384 + tid;
        const float* ps = PS + (size_t)sb2 * NCHUNK * 3072 + dn * 2;
        float* Ip = I + (size_t)sb2 * NCHUNK * 1536 + dn;
        float st = 0.f;
        for (int c = 0; c < NCHUNK; c += 8) {
            float2 v[8];
#pragma unroll
            for (int q = 0; q < 8; q++) v[q] = *(const float2*)&ps[(size_t)(c + q) * 3072];
#pragma unroll
            for (int q = 0; q < 8; q++) { Ip[(size_t)(c + q) * 1536] = st; st = v[q].x * st + v[q].y; }
        }
    }
    __threadfence();
    cg::this_grid().sync();
    // ---- phase C: re-scan from LDS with true init + fused epilogue ----
    {
        f32x4 si = *(const f32x4*)&I[(size_t)(sb * NCHUNK + chunk) * 1536 + d * 4];
#pragma unroll
        for (int n = 0; n < NST; n++) s[n] = si[n];
    }
    float Dv = Dp[d];
    for (int t = 0; t < TSTEP; t++) {
        float dtv = bf2f(ds_dt[t * DI + d]);
        float uv = bf2f(ds_u[t * DI + d]);
        float dtu = dtv * uv;
        float y = 0.f;
#pragma unroll
        for (int n = 0; n < NST; n++) {
            float dA = __expf(dtv * a[n]);
            s[n] = dA * s[n] + dtu * ds_bc[t * 8 + n];
            y += s[n] * ds_bc[t * 8 + 4 + n];
        }
        float gt = bf2f(hg[(size_t)(base + t) * 768 + 384 + d]);
        float sg = gt * __builtin_amdgcn_rcpf(1.f + __expf(-gt));
        ymix[(size_t)(base + t) * DI + d] = f2bf((y + uv * Dv) * sg);
    }
}

// ---------------- gate softmax (block 0) + inverse permutation (blocks 1..16) ----------------
__global__ __launch_bounds__(384) void gate_inv(const float* __restrict__ means,
                                                const float* __restrict__ gw,
                                                float* __restrict__ g,
                                                const int* __restrict__ ridx,
                                                int* __restrict__ inv)
{
    if (blockIdx.x == 0) {
        int lane = threadIdx.x & 63, p = threadIdx.x >> 6;
        int bb = p / 3, j = p % 3;
        float part = 0.f;
        for (int i = lane; i < 384; i += 64) {
            int s = i >> 7, c = i & 127;
            part += means[(s * 2 + bb) * 128 + c] * (1.f / 4096.f) * gw[j * 384 + i];
        }
        part = wave_sum(part);
        __shared__ float lg[6];
        if (lane == 0) lg[p] = part;
        __syncthreads();
        if (threadIdx.x < 2) {
            int b2 = threadIdx.x;
            float a0 = lg[b2 * 3], a1 = lg[b2 * 3 + 1], a2 = lg[b2 * 3 + 2];
            float mx = fmaxf(a0, fmaxf(a1, a2));
            float e0 = __expf(a0 - mx), e1 = __expf(a1 - mx), e2 = __expf(a2 - mx);
            float iv = __builtin_amdgcn_rcpf(e0 + e1 + e2);
            g[b2 * 3] = e0 * iv; g[b2 * 3 + 1] = e1 * iv; g[b2 * 3 + 2] = e2 * iv;
        }
    } else {
        if (threadIdx.x < 256) {
            int l = (blockIdx.x - 1) * 256 + threadIdx.x;
            inv[ridx[l]] = l;
        }
    }
}

// combine 3 directions + residual + LayerNorm2 (4 rows/block)
__global__ __launch_bounds__(256) void combine_ln2(const float* __restrict__ x,
                                                   const float* __restrict__ y6,
                                                   const float* __restrict__ g,
                                                   const int* __restrict__ inv,
                                                   const float* __restrict__ n2g,
                                                   const float* __restrict__ n2b,
                                                   float* __restrict__ x1,
                                                   short* __restrict__ xn2)
{
    int r = blockIdx.x * 4 + (threadIdx.x >> 6);
    int lane = threadIdx.x & 63;
    int bb = r / LLEN, l = r % LLEN;
    float g0 = g[bb * 3 + 0], g1 = g[bb * 3 + 1], g2 = g[bb * 3 + 2];
    int il = inv[l];
    size_t fo = ((size_t)(0 + bb) * LLEN + l) * CCH;
    size_t ro = ((size_t)(2 + bb) * LLEN + (LLEN - 1 - l)) * CCH;
    size_t so = ((size_t)(4 + bb) * LLEN + il) * CCH;
    size_t xo = ((size_t)bb * LLEN + l) * CCH;
    float v0 = x[xo + lane]      + g0 * y6[fo + lane]      + g1 * y6[ro + lane]      + g2 * y6[so + lane];
    float v1 = x[xo + lane + 64] + g0 * y6[fo + lane + 64] + g1 * y6[ro + lane + 64] + g2 * y6[so + lane + 64];
    float m = wave_sum(v0 + v1) * (1.f / 128.f);
    float d0 = v0 - m, d1 = v1 - m;
    float var = wave_sum(d0 * d0 + d1 * d1) * (1.f / 128.f);
    float rstd = rsqrtf(var + 1e-5f);
    x1[xo + lane] = v0; x1[xo + lane + 64] = v1;
    xn2[xo + lane]      = f2bf(d0 * rstd * n2g[lane]      + n2b[lane]);
    xn2[xo + lane + 64] = f2bf(d1 * rstd * n2g[lane + 64] + n2b[lane + 64]);
}

// ---------------- 3x3 depthwise conv + exact GeLU: sliding-window vectorized ----------------
__global__ __launch_bounds__(256) void peconv_gelu_v2(const short* __restrict__ t,
                                                      const float* __restrict__ pw,
                                                      const float* __restrict__ pb,
                                                      short* __restrict__ t2)
{
    int tid = threadIdx.x;
    int fc = tid & 127;
    int wsr = tid >> 7;
    int blk = blockIdx.x;
    int whalf = blk & 1, h = (blk >> 1) & 63, bb = blk >> 7;
    int w0 = whalf * 32 + wsr * 16;
    int f0 = fc * 4;
    float wt[9][4], bias4[4];
#pragma unroll
    for (int e = 0; e < 4; e++) {
        bias4[e] = pb[f0 + e];
#pragma unroll
        for (int k = 0; k < 9; k++) wt[k][e] = pw[(f0 + e) * 9 + k];
    }
    size_t base = (size_t)bb * 4096 * FCH;
    float cm1[3][4], cc[3][4], cn[3][4];
#pragma unroll
    for (int rr = 0; rr < 3; rr++)
#pragma unroll
        for (int e = 0; e < 4; e++) { cm1[rr][e] = 0.f; cc[rr][e] = 0.f; }
#pragma unroll
    for (int rr = 0; rr < 3; rr++) {
        int hh = h + rr - 1;
        if (hh >= 0 && hh < 64) {
            if (w0 - 1 >= 0) {
                bf16x4 v = *(const bf16x4*)&t[base + ((size_t)hh * 64 + (w0 - 1)) * FCH + f0];
#pragma unroll
                for (int e = 0; e < 4; e++) cm1[rr][e] = bf2f(v[e]);
            }
            bf16x4 v = *(const bf16x4*)&t[base + ((size_t)hh * 64 + w0) * FCH + f0];
#pragma unroll
            for (int e = 0; e < 4; e++) cc[rr][e] = bf2f(v[e]);
        }
    }
#pragma unroll
    for (int i = 0; i < 16; i++) {
        int w = w0 + i;
#pragma unroll
        for (int rr = 0; rr < 3; rr++) {
#pragma unroll
            for (int e = 0; e < 4; e++) cn[rr][e] = 0.f;
            int hh = h + rr - 1;
            if (hh >= 0 && hh < 64 && w + 1 < 64) {
                bf16x4 v = *(const bf16x4*)&t[base + ((size_t)hh * 64 + (w + 1)) * FCH + f0];
#pragma unroll
                for (int e = 0; e < 4; e++) cn[rr][e] = bf2f(v[e]);
            }
        }
        bf16x4 ov;
#pragma unroll
        for (int e = 0; e < 4; e++) {
            float acc = bias4[e];
#pragma unroll
            for (int rr = 0; rr < 3; rr++) {
                acc += wt[rr * 3 + 0][e] * cm1[rr][e];
                acc += wt[rr * 3 + 1][e] * cc[rr][e];
                acc += wt[rr * 3 + 2][e] * cn[rr][e];
            }
            ov[e] = f2bf(0.5f * acc * (1.f + erff(acc * 0.70710678118654752f)));
        }
        *(bf16x4*)&t2[base + ((size_t)h * 64 + w) * FCH + f0] = ov;
#pragma unroll
        for (int rr = 0; rr < 3; rr++)
#pragma unroll
            for (int e = 0; e < 4; e++) { cm1[rr][e] = cc[rr][e]; cc[rr][e] = cn[rr][e]; }
    }
}

extern "C" void kernel_launch(void* const* d_in, const int* in_sizes, int n_in,
                              void* d_out, int out_size, void* d_ws, size_t ws_size,
                              hipStream_t stream)
{
    (void)in_sizes; (void)n_in; (void)ws_size; (void)out_size;
    const float* x      = (const float*)d_in[0];
    const int*   ridx   = (const int*)d_in[1];
    const float* n1g    = (const float*)d_in[4];
    const float* n1b    = (const float*)d_in[5];
    const float* in_w   = (const float*)d_in[6];
    const float* conv_w = (const float*)d_in[7];
    const float* conv_b = (const float*)d_in[8];
    const float* xp_w   = (const float*)d_in[9];
    const float* dt_w   = (const float*)d_in[10];
    const float* dt_b   = (const float*)d_in[11];
    const float* A_log  = (const float*)d_in[12];
    const float* Dp     = (const float*)d_in[13];
    const float* out_w  = (const float*)d_in[14];
    const float* n2g    = (const float*)d_in[15];
    const float* n2b    = (const float*)d_in[16];
    const float* gate_w = (const float*)d_in[17];
    const float* fc1_w  = (const float*)d_in[18];
    const float* fc1_b  = (const float*)d_in[19];
    const float* pe_w   = (const float*)d_in[20];
    const float* pe_b   = (const float*)d_in[21];
    const float* fc2_w  = (const float*)d_in[22];
    const float* fc2_b  = (const float*)d_in[23];
    float* out = (float*)d_out;

    float* ws = (float*)d_ws;
    short* wb   = (short*)ws;                       // [0, 215040)
    float* regA = ws + 215040;                      // xn(bf16) -> I(f32) -> tbuf(bf16)   [2,097,152]
    float* regB = regA + 2097152;                   // hg(bf16) -> {y6,x1,xn2,t2}         [9,437,184]
    float* regC = regB + 9437184;                   // ub(bf16)                           [4,718,592]
    float* regD = regC + 4718592;                   // ymix(bf16)                         [4,718,592]
    float* regE = regD + 4718592;                   // dtb(bf16)                          [4,718,592]
    float* regF = regE + 4718592;                   // PS (f32 pairs)                     [2,359,296]
    float* regG = regF + 2359296;                   // xpbc (f32)                         [196,608]
    float* smallb = regG + 196608;

    short* xn   = (short*)regA;
    float* Ibuf = regA;
    short* tbuf = (short*)regA;
    short* hg   = (short*)regB;
    float* y6   = regB;
    float* x1   = regB + 3145728;
    short* xn2  = (short*)(regB + 4194304);
    short* t2   = (short*)(regB + 4718592);
    short* ub   = (short*)regC;
    short* ymix = (short*)regD;
    short* dtb  = (short*)regE;
    float* PS   = regF;
    float* xpbc = regG;
    float* means = smallb;
    float* gbuf  = smallb + 768;
    int*   invb  = (int*)(gbuf + 8);

    const int M6 = SBN * LLEN;   // 24576
    const int M2 = NB * LLEN;    // 8192

    conv_comp<<<NCBLK + 576, 256, 0, stream>>>(in_w, xp_w, dt_w, out_w, fc1_w, fc2_w, wb);
    hipMemsetAsync(means, 0, 768 * sizeof(float), stream);
    prep_ln1<<<M6 / 4, 256, 0, stream>>>(x, ridx, n1g, n1b, xn);
    // fused in_proj: [h | gate] N=768, bf16 out
    gemm_w<5><<<dim3(M6 / 64, 6), 256, 0, stream>>>(xn, CCH, wb + OFF_IN, CCH, 768, nullptr, nullptr, 0, nullptr, hg, 768, nullptr, CCH);
    dwconv_silu_v2<<<768, 192, 0, stream>>>(hg, conv_w, conv_b, ub);
    // merged dt(softplus, bf16) + B/C(f32) projection: N=392
    gemm_w<7><<<dim3(M6 / 64, 4), 256, 0, stream>>>(ub, DI, wb + OFF_DTC, DI, 392, dt_b, nullptr, 0, nullptr, dtb, DI, xpbc, DI);
    // cooperative fused selective scan
    {
        void* sargs[] = { (void*)&dtb, (void*)&xpbc, (void*)&ub, (void*)&hg,
                          (void*)&A_log, (void*)&Dp, (void*)&PS, (void*)&Ibuf, (void*)&ymix };
        hipLaunchCooperativeKernel((void*)scan_fused, dim3(SBN * NCHUNK), dim3(DI), sargs, 0, stream);
    }
    // out_proj + fused column sums
    gemm_w<8><<<dim3(M6 / 64, 1), 256, 0, stream>>>(ymix, DI, wb + OFF_OUT, DI, CCH, nullptr, nullptr, 0, y6, nullptr, CCH, means, DI);
    gate_inv<<<17, 384, 0, stream>>>(means, gate_w, gbuf, ridx, invb);
    combine_ln2<<<M2 / 4, 256, 0, stream>>>(x, y6, gbuf, invb, n2g, n2b, x1, xn2);
    // MixFFN
    gemm_w<6><<<dim3(M2 / 64, 4), 256, 0, stream>>>(xn2, CCH, wb + OFF_FC1, CCH, FCH, fc1_b, nullptr, 0, nullptr, tbuf, FCH, nullptr, CCH);
    peconv_gelu_v2<<<256, 256, 0, stream>>>(tbuf, pe_w, pe_b, t2);
    gemm_w<3><<<dim3(M2 / 64, 1), 256, 0, stream>>>(t2, FCH, wb + OFF_FC2, FCH, CCH, fc2_b, x1, CCH, out, nullptr, CCH, nullptr, FCH);
}

// Round 6
// 183.007 us; speedup vs baseline: 2.9559x; 2.9559x over previous
//
#include <hip/hip_runtime.h>
#include <math.h>

#define LLEN 4096
#define CCH 128
#define DI 384
#define NST 4
#define SBN 6        // 3 directions x B=2
#define NB 2
#define FCH 512
#define NCHUNK 128
#define TSTEP 32

typedef short bf16x8 __attribute__((ext_vector_type(8)));
typedef short bf16x4 __attribute__((ext_vector_type(4)));
typedef float f32x4 __attribute__((ext_vector_type(4)));
typedef float f32x8 __attribute__((ext_vector_type(8)));

__device__ __forceinline__ float wave_sum(float v) {
#pragma unroll
    for (int o = 32; o > 0; o >>= 1) v += __shfl_xor(v, o);
    return v;
}

__device__ __forceinline__ short f2bf(float f) {
    unsigned int u = __float_as_uint(f);
    unsigned int r = (u + 0x7fffu + ((u >> 16) & 1u)) >> 16;
    return (short)r;
}
__device__ __forceinline__ float bf2f(short s) {
    return __uint_as_float(((unsigned int)(unsigned short)s) << 16);
}

// ---------------- weight bf16 pool offsets (elements) ----------------
#define OFF_IN  0         // in_w                 768x128
#define OFF_DTC 98304     // composed dt_w@xp_w[:128]  384x384 (rows 0..383)
#define OFF_BC  245760    //   + xp_w rows 128..135 as rows 384..391 (same ld=384)
#define OFF_OUT 248832    // out_w                128x384
#define OFF_FC1 297984    // fc1_w                512x128
#define OFF_FC2 363520    // fc2_w                128x512
#define OFF_END 429056
#define NCONV   281600    // convertible elements (everything except DTC region)
#define NCBLK   1100      // ceil(281600/256)

// merged: plain conversions + dt_w@xp_w composition
__global__ __launch_bounds__(256) void conv_comp(const float* __restrict__ in_w,
                                                 const float* __restrict__ xp_w,
                                                 const float* __restrict__ dt_w,
                                                 const float* __restrict__ out_w,
                                                 const float* __restrict__ fc1_w,
                                                 const float* __restrict__ fc2_w,
                                                 short* __restrict__ wb)
{
    int bid = blockIdx.x;
    if (bid < NCBLK) {
        int i = bid * 256 + threadIdx.x;
        if (i >= NCONV) return;
        int idx = (i < OFF_DTC) ? i : i + (OFF_OUT - OFF_DTC);  // skip composed region
        float v;
        if (idx < OFF_DTC)      v = in_w[idx];
        else if (idx < OFF_OUT) v = xp_w[128 * 384 + (idx - OFF_BC)];   // bc rows
        else if (idx < OFF_FC1) v = out_w[idx - OFF_OUT];
        else if (idx < OFF_FC2) v = fc1_w[idx - OFF_FC1];
        else                    v = fc2_w[idx - OFF_FC2];
        wb[idx] = f2bf(v);
    } else {
        int ji = (bid - NCBLK) * 256 + threadIdx.x;   // 0 .. 147455
        int j = ji / 384, k = ji % 384;
        float acc = 0.f;
#pragma unroll 8
        for (int n = 0; n < 128; n++)
            acc += dt_w[j * 128 + n] * xp_w[n * 384 + k];
        wb[OFF_DTC + j * 384 + k] = f2bf(acc);
    }
}

// ---------------- LayerNorm over C=128, FWD rows only (perm invariance), 4 rows/block ----------------
__global__ __launch_bounds__(256) void prep_ln1(const float* __restrict__ x,
                                                const float* __restrict__ g,
                                                const float* __restrict__ b,
                                                short* __restrict__ xn)
{
    int r = blockIdx.x * 4 + (threadIdx.x >> 6);   // 0 .. 8191
    int lane = threadIdx.x & 63;
    const float* src = x + (size_t)r * CCH;
    float v0 = src[lane], v1 = src[lane + 64];
    float m = wave_sum(v0 + v1) * (1.f / 128.f);
    float d0 = v0 - m, d1 = v1 - m;
    float var = wave_sum(d0 * d0 + d1 * d1) * (1.f / 128.f);
    float rstd = rsqrtf(var + 1e-5f);
    short* dst = xn + (size_t)r * CCH;
    dst[lane]      = f2bf(d0 * rstd * g[lane]      + b[lane]);
    dst[lane + 64] = f2bf(d1 * rstd * g[lane + 64] + b[lane + 64]);
}

// ---------------- wide MFMA GEMM (64x128 tile) ----------------
// EPI: 3=bias+residual f32   5=bf16   6=bias bf16
//      7=dtc+bc split: col<384 bias+softplus bf16 -> Cb; col 384..391 f32 -> extra
//      8=f32 out + per-column block sums atomically added to extra (means)
template<int EPI>
__global__ __launch_bounds__(256) void gemm_w(const short* __restrict__ A, int lda,
                                              const short* __restrict__ W, int ldw, int Ntot,
                                              const float* __restrict__ bias,
                                              const float* __restrict__ res, int ldr,
                                              float* __restrict__ C0,
                                              short* __restrict__ Cb, int ldc,
                                              float* __restrict__ extra,
                                              int Kd)
{
    __shared__ short Als[64 * 72];
    __shared__ short Wls[128 * 72];
    int tid = threadIdx.x;
    int wid = tid >> 6, lane = tid & 63;
    int wm = wid >> 1, wn = wid & 1;
    int l15 = lane & 15, l4 = lane >> 4;
    int bm = blockIdx.x * 64, bn = blockIdx.y * 128;
    int srow = tid >> 3, scol = (tid & 7) * 8;
    f32x4 acc[2][4] = {};
    for (int k0 = 0; k0 < Kd; k0 += 64) {
        bf16x8 av0 = *(const bf16x8*)&A[(size_t)(bm + srow) * lda + k0 + scol];
        bf16x8 av1 = *(const bf16x8*)&A[(size_t)(bm + srow + 32) * lda + k0 + scol];
        bf16x8 wv[4];
#pragma unroll
        for (int q = 0; q < 4; q++) {
            if (EPI == 7) {
                wv[q] = bf16x8{};
                if (bn + srow + 32 * q < Ntot)
                    wv[q] = *(const bf16x8*)&W[(size_t)(bn + srow + 32 * q) * ldw + k0 + scol];
            } else {
                wv[q] = *(const bf16x8*)&W[(size_t)(bn + srow + 32 * q) * ldw + k0 + scol];
            }
        }
        __syncthreads();
        *(bf16x8*)&Als[srow * 72 + scol] = av0;
        *(bf16x8*)&Als[(srow + 32) * 72 + scol] = av1;
#pragma unroll
        for (int q = 0; q < 4; q++)
            *(bf16x8*)&Wls[(srow + 32 * q) * 72 + scol] = wv[q];
        __syncthreads();
#pragma unroll
        for (int ks = 0; ks < 2; ks++) {
            bf16x8 af[2], bw[4];
#pragma unroll
            for (int f = 0; f < 2; f++)
                af[f] = *(const bf16x8*)&Als[(wm * 32 + f * 16 + l15) * 72 + ks * 32 + l4 * 8];
#pragma unroll
            for (int j = 0; j < 4; j++)
                bw[j] = *(const bf16x8*)&Wls[(wn * 64 + j * 16 + l15) * 72 + ks * 32 + l4 * 8];
#pragma unroll
            for (int i = 0; i < 2; i++)
#pragma unroll
                for (int j = 0; j < 4; j++)
                    acc[i][j] = __builtin_amdgcn_mfma_f32_16x16x32_bf16(af[i], bw[j], acc[i][j], 0, 0, 0);
        }
    }
    __shared__ float cs[128];
    if (EPI == 8) {
        if (tid < 128) cs[tid] = 0.f;
        __syncthreads();
    }
#pragma unroll
    for (int i = 0; i < 2; i++) {
        int row0 = bm + wm * 32 + i * 16 + l4 * 4;
#pragma unroll
        for (int j = 0; j < 4; j++) {
            int col = bn + wn * 64 + j * 16 + l15;
            if (EPI == 7) {
                if (col < 384) {
                    float bv = bias[col];
#pragma unroll
                    for (int r = 0; r < 4; r++) {
                        float v = acc[i][j][r] + bv;
                        v = (v > 20.f) ? v : __logf(1.f + __expf(v));
                        Cb[(size_t)(row0 + r) * ldc + col] = f2bf(v);
                    }
                } else if (col < 392) {
#pragma unroll
                    for (int r = 0; r < 4; r++)
                        extra[(size_t)(row0 + r) * 8 + (col - 384)] = acc[i][j][r];
                }
            } else {
                float bv = (EPI == 3 || EPI == 6) ? bias[col] : 0.f;
                float csum = 0.f;
#pragma unroll
                for (int r = 0; r < 4; r++) {
                    float v = acc[i][j][r] + bv;
                    if (EPI == 3) v += res[(size_t)(row0 + r) * ldr + col];
                    if (EPI == 5 || EPI == 6)
                        Cb[(size_t)(row0 + r) * ldc + col] = f2bf(v);
                    else
                        C0[(size_t)(row0 + r) * ldc + col] = v;
                    csum += v;
                }
                if (EPI == 8) atomicAdd(&cs[wn * 64 + j * 16 + l15], csum);
            }
        }
    }
    if (EPI == 8) {
        __syncthreads();
        if (tid < 128) atomicAdd(&extra[(bm >> 12) * 128 + tid], cs[tid]);
    }
}

// ---------------- depthwise causal conv K=4 + bias + SiLU over permuted views of hg_fwd ----------------
// hg is FWD-only [8192 x 768]; direction handled by row gather (sliding window still 1 new row/step).
__global__ __launch_bounds__(192) void dwconv_silu_v3(const short* __restrict__ hg,
                                                      const int* __restrict__ ridx,
                                                      const float* __restrict__ cw,
                                                      const float* __restrict__ cb,
                                                      short* __restrict__ ub)
{
    int t = threadIdx.x;
    int c = t % 48, rs = t / 48;
    int blk = blockIdx.x;            // 768 blocks: 6 sb x 128
    int sb = blk >> 7;
    int s = sb >> 1, bb = sb & 1;
    int l0 = ((blk & 127) << 5) + rs * 8;
    int d0 = c * 8;
    float w0[8], w1[8], w2[8], w3[8], bs[8];
#pragma unroll
    for (int e = 0; e < 8; e++) {
        int d = d0 + e;
        bs[e] = cb[d];
        w0[e] = cw[d * 4 + 0]; w1[e] = cw[d * 4 + 1];
        w2[e] = cw[d * 4 + 2]; w3[e] = cw[d * 4 + 3];
    }
    float r0[8], r1[8], r2[8];
#pragma unroll
    for (int e = 0; e < 8; e++) { r0[e] = 0.f; r1[e] = 0.f; r2[e] = 0.f; }
    if (l0 - 3 >= 0) {
        int j = l0 - 3;
        int sl = (s == 0) ? j : (s == 1 ? LLEN - 1 - j : ridx[j]);
        bf16x8 v = *(const bf16x8*)&hg[(size_t)(bb * LLEN + sl) * 768 + d0];
#pragma unroll
        for (int e = 0; e < 8; e++) r0[e] = bf2f(v[e]);
    }
    if (l0 - 2 >= 0) {
        int j = l0 - 2;
        int sl = (s == 0) ? j : (s == 1 ? LLEN - 1 - j : ridx[j]);
        bf16x8 v = *(const bf16x8*)&hg[(size_t)(bb * LLEN + sl) * 768 + d0];
#pragma unroll
        for (int e = 0; e < 8; e++) r1[e] = bf2f(v[e]);
    }
    if (l0 - 1 >= 0) {
        int j = l0 - 1;
        int sl = (s == 0) ? j : (s == 1 ? LLEN - 1 - j : ridx[j]);
        bf16x8 v = *(const bf16x8*)&hg[(size_t)(bb * LLEN + sl) * 768 + d0];
#pragma unroll
        for (int e = 0; e < 8; e++) r2[e] = bf2f(v[e]);
    }
#pragma unroll
    for (int i = 0; i < 8; i++) {
        int j = l0 + i;
        int sl = (s == 0) ? j : (s == 1 ? LLEN - 1 - j : ridx[j]);
        bf16x8 v = *(const bf16x8*)&hg[(size_t)(bb * LLEN + sl) * 768 + d0];
        float r3[8];
#pragma unroll
        for (int e = 0; e < 8; e++) r3[e] = bf2f(v[e]);
        bf16x8 ov;
#pragma unroll
        for (int e = 0; e < 8; e++) {
            float a = bs[e] + w0[e] * r0[e] + w1[e] * r1[e] + w2[e] * r2[e] + w3[e] * r3[e];
            ov[e] = f2bf(a * __builtin_amdgcn_rcpf(1.f + __expf(-a)));
        }
        *(bf16x8*)&ub[(size_t)(sb * LLEN + j) * DI + d0] = ov;
#pragma unroll
        for (int e = 0; e < 8; e++) { r0[e] = r1[e]; r1[e] = r2[e]; r2[e] = r3[e]; }
    }
}

// ---------------- scan phase A: per-chunk zero-init scan, LDS-staged ----------------
__global__ __launch_bounds__(DI) void scan_phaseA2(const short* __restrict__ dtb,
                                                   const float* __restrict__ bc,
                                                   const short* __restrict__ ub,
                                                   const float* __restrict__ A_log,
                                                   float* __restrict__ PS)
{
    __shared__ short ds_dt[TSTEP * DI];
    __shared__ short ds_u[TSTEP * DI];
    __shared__ float ds_bc[TSTEP * 8];
    int tid = threadIdx.x;
    int bid = blockIdx.x;
    int sb = bid / NCHUNK, chunk = bid % NCHUNK;
    int base = sb * LLEN + chunk * TSTEP;
    {
        int rr = tid / 48, cc = (tid % 48) * 8;
#pragma unroll
        for (int p = 0; p < 4; p++) {
            int row = p * 8 + rr;
            *(bf16x8*)&ds_dt[row * DI + cc] = *(const bf16x8*)&dtb[(size_t)(base + row) * DI + cc];
            *(bf16x8*)&ds_u[row * DI + cc]  = *(const bf16x8*)&ub[(size_t)(base + row) * DI + cc];
        }
        if (tid < TSTEP * 8) ds_bc[tid] = bc[(size_t)base * 8 + tid];
    }
    int d = tid;
    f32x4 al = *(const f32x4*)&A_log[d * 4];
    float a[NST];
#pragma unroll
    for (int n = 0; n < NST; n++) a[n] = -__expf(al[n]);
    __syncthreads();
    float s[NST] = {0.f, 0.f, 0.f, 0.f}, p[NST] = {1.f, 1.f, 1.f, 1.f};
    for (int t = 0; t < TSTEP; t++) {
        float dtv = bf2f(ds_dt[t * DI + d]);
        float dtu = dtv * bf2f(ds_u[t * DI + d]);
#pragma unroll
        for (int n = 0; n < NST; n++) {
            float dA = __expf(dtv * a[n]);
            s[n] = dA * s[n] + dtu * ds_bc[t * 8 + n];
            p[n] *= dA;
        }
    }
    f32x8 v;
#pragma unroll
    for (int n = 0; n < NST; n++) { v[2 * n] = p[n]; v[2 * n + 1] = s[n]; }
    *(f32x8*)&PS[(size_t)(sb * NCHUNK + chunk) * 3072 + d * 8] = v;
}

// ---------------- scan phase B: cross-chunk prefix ----------------
__global__ __launch_bounds__(256) void scan_phaseB2(const float* __restrict__ PS,
                                                    float* __restrict__ I)
{
    int gid = blockIdx.x * 256 + threadIdx.x;
    if (gid >= SBN * 1536) return;
    int sb = gid / 1536, dn = gid % 1536;
    const float* ps = PS + (size_t)sb * NCHUNK * 3072 + dn * 2;
    float* Ip = I + (size_t)sb * NCHUNK * 1536 + dn;
    float st = 0.f;
    for (int c = 0; c < NCHUNK; c += 8) {
        float2 v[8];
#pragma unroll
        for (int q = 0; q < 8; q++) v[q] = *(const float2*)&ps[(size_t)(c + q) * 3072];
#pragma unroll
        for (int q = 0; q < 8; q++) { Ip[(size_t)(c + q) * 1536] = st; st = v[q].x * st + v[q].y; }
    }
}

// ---------------- scan phase C: re-scan with true init + fused epilogue ----------------
__global__ __launch_bounds__(DI) void scan_phaseC2(const short* __restrict__ dtb,
                                                   const float* __restrict__ bc,
                                                   const short* __restrict__ ub,
                                                   const short* __restrict__ hg,
                                                   const int* __restrict__ ridx,
                                                   const float* __restrict__ A_log,
                                                   const float* __restrict__ Dp,
                                                   const float* __restrict__ I,
                                                   short* __restrict__ ymix)
{
    __shared__ short ds_dt[TSTEP * DI];
    __shared__ short ds_u[TSTEP * DI];
    __shared__ float ds_bc[TSTEP * 8];
    __shared__ int ds_src[TSTEP];
    int tid = threadIdx.x;
    int bid = blockIdx.x;
    int sb = bid / NCHUNK, chunk = bid % NCHUNK;
    int s2 = sb >> 1, bb = sb & 1;
    int base = sb * LLEN + chunk * TSTEP;
    {
        int rr = tid / 48, cc = (tid % 48) * 8;
#pragma unroll
        for (int p = 0; p < 4; p++) {
            int row = p * 8 + rr;
            *(bf16x8*)&ds_dt[row * DI + cc] = *(const bf16x8*)&dtb[(size_t)(base + row) * DI + cc];
            *(bf16x8*)&ds_u[row * DI + cc]  = *(const bf16x8*)&ub[(size_t)(base + row) * DI + cc];
        }
        if (tid < TSTEP * 8) ds_bc[tid] = bc[(size_t)base * 8 + tid];
        if (tid < TSTEP) {
            int l = chunk * TSTEP + tid;
            int sl = (s2 == 0) ? l : (s2 == 1 ? LLEN - 1 - l : ridx[l]);
            ds_src[tid] = bb * LLEN + sl;
        }
    }
    int d = tid;
    f32x4 al = *(const f32x4*)&A_log[d * 4];
    float a[NST];
#pragma unroll
    for (int n = 0; n < NST; n++) a[n] = -__expf(al[n]);
    __syncthreads();
    float s[NST];
    {
        f32x4 si = *(const f32x4*)&I[(size_t)(sb * NCHUNK + chunk) * 1536 + d * 4];
#pragma unroll
        for (int n = 0; n < NST; n++) s[n] = si[n];
    }
    float Dv = Dp[d];
    for (int t = 0; t < TSTEP; t++) {
        float dtv = bf2f(ds_dt[t * DI + d]);
        float uv = bf2f(ds_u[t * DI + d]);
        float dtu = dtv * uv;
        float y = 0.f;
#pragma unroll
        for (int n = 0; n < NST; n++) {
            float dA = __expf(dtv * a[n]);
            s[n] = dA * s[n] + dtu * ds_bc[t * 8 + n];
            y += s[n] * ds_bc[t * 8 + 4 + n];
        }
        float gt = bf2f(hg[(size_t)ds_src[t] * 768 + 384 + d]);
        float sg = gt * __builtin_amdgcn_rcpf(1.f + __expf(-gt));
        ymix[(size_t)(base + t) * DI + d] = f2bf((y + uv * Dv) * sg);
    }
}

// ---------------- gate softmax (block 0) + inverse permutation (blocks 1..16) ----------------
__global__ __launch_bounds__(384) void gate_inv(const float* __restrict__ means,
                                                const float* __restrict__ gw,
                                                float* __restrict__ g,
                                                const int* __restrict__ ridx,
                                                int* __restrict__ inv)
{
    if (blockIdx.x == 0) {
        int lane = threadIdx.x & 63, p = threadIdx.x >> 6;
        int bb = p / 3, j = p % 3;
        float part = 0.f;
        for (int i = lane; i < 384; i += 64) {
            int s = i >> 7, c = i & 127;
            part += means[(s * 2 + bb) * 128 + c] * (1.f / 4096.f) * gw[j * 384 + i];
        }
        part = wave_sum(part);
        __shared__ float lg[6];
        if (lane == 0) lg[p] = part;
        __syncthreads();
        if (threadIdx.x < 2) {
            int b2 = threadIdx.x;
            float a0 = lg[b2 * 3], a1 = lg[b2 * 3 + 1], a2 = lg[b2 * 3 + 2];
            float mx = fmaxf(a0, fmaxf(a1, a2));
            float e0 = __expf(a0 - mx), e1 = __expf(a1 - mx), e2 = __expf(a2 - mx);
            float iv = __builtin_amdgcn_rcpf(e0 + e1 + e2);
            g[b2 * 3] = e0 * iv; g[b2 * 3 + 1] = e1 * iv; g[b2 * 3 + 2] = e2 * iv;
        }
    } else {
        if (threadIdx.x < 256) {
            int l = (blockIdx.x - 1) * 256 + threadIdx.x;
            inv[ridx[l]] = l;
        }
    }
}

// combine 3 directions + residual + LayerNorm2 (4 rows/block)
__global__ __launch_bounds__(256) void combine_ln2(const float* __restrict__ x,
                                                   const float* __restrict__ y6,
                                                   const float* __restrict__ g,
                                                   const int* __restrict__ inv,
                                                   const float* __restrict__ n2g,
                                                   const float* __restrict__ n2b,
                                                   float* __restrict__ x1,
                                                   short* __restrict__ xn2)
{
    int r = blockIdx.x * 4 + (threadIdx.x >> 6);
    int lane = threadIdx.x & 63;
    int bb = r / LLEN, l = r % LLEN;
    float g0 = g[bb * 3 + 0], g1 = g[bb * 3 + 1], g2 = g[bb * 3 + 2];
    int il = inv[l];
    size_t fo = ((size_t)(0 + bb) * LLEN + l) * CCH;
    size_t ro = ((size_t)(2 + bb) * LLEN + (LLEN - 1 - l)) * CCH;
    size_t so = ((size_t)(4 + bb) * LLEN + il) * CCH;
    size_t xo = ((size_t)bb * LLEN + l) * CCH;
    float v0 = x[xo + lane]      + g0 * y6[fo + lane]      + g1 * y6[ro + lane]      + g2 * y6[so + lane];
    float v1 = x[xo + lane + 64] + g0 * y6[fo + lane + 64] + g1 * y6[ro + lane + 64] + g2 * y6[so + lane + 64];
    float m = wave_sum(v0 + v1) * (1.f / 128.f);
    float d0 = v0 - m, d1 = v1 - m;
    float var = wave_sum(d0 * d0 + d1 * d1) * (1.f / 128.f);
    float rstd = rsqrtf(var + 1e-5f);
    x1[xo + lane] = v0; x1[xo + lane + 64] = v1;
    xn2[xo + lane]      = f2bf(d0 * rstd * n2g[lane]      + n2b[lane]);
    xn2[xo + lane + 64] = f2bf(d1 * rstd * n2g[lane + 64] + n2b[lane + 64]);
}

// ---------------- 3x3 depthwise conv + exact GeLU: sliding-window vectorized ----------------
__global__ __launch_bounds__(256) void peconv_gelu_v2(const short* __restrict__ t,
                                                      const float* __restrict__ pw,
                                                      const float* __restrict__ pb,
                                                      short* __restrict__ t2)
{
    int tid = threadIdx.x;
    int fc = tid & 127;
    int wsr = tid >> 7;
    int blk = blockIdx.x;
    int whalf = blk & 1, h = (blk >> 1) & 63, bb = blk >> 7;
    int w0 = whalf * 32 + wsr * 16;
    int f0 = fc * 4;
    float wt[9][4], bias4[4];
#pragma unroll
    for (int e = 0; e < 4; e++) {
        bias4[e] = pb[f0 + e];
#pragma unroll
        for (int k = 0; k < 9; k++) wt[k][e] = pw[(f0 + e) * 9 + k];
    }
    size_t base = (size_t)bb * 4096 * FCH;
    float cm1[3][4], cc[3][4], cn[3][4];
#pragma unroll
    for (int rr = 0; rr < 3; rr++)
#pragma unroll
        for (int e = 0; e < 4; e++) { cm1[rr][e] = 0.f; cc[rr][e] = 0.f; }
#pragma unroll
    for (int rr = 0; rr < 3; rr++) {
        int hh = h + rr - 1;
        if (hh >= 0 && hh < 64) {
            if (w0 - 1 >= 0) {
                bf16x4 v = *(const bf16x4*)&t[base + ((size_t)hh * 64 + (w0 - 1)) * FCH + f0];
#pragma unroll
                for (int e = 0; e < 4; e++) cm1[rr][e] = bf2f(v[e]);
            }
            bf16x4 v = *(const bf16x4*)&t[base + ((size_t)hh * 64 + w0) * FCH + f0];
#pragma unroll
            for (int e = 0; e < 4; e++) cc[rr][e] = bf2f(v[e]);
        }
    }
#pragma unroll
    for (int i = 0; i < 16; i++) {
        int w = w0 + i;
#pragma unroll
        for (int rr = 0; rr < 3; rr++) {
#pragma unroll
            for (int e = 0; e < 4; e++) cn[rr][e] = 0.f;
            int hh = h + rr - 1;
            if (hh >= 0 && hh < 64 && w + 1 < 64) {
                bf16x4 v = *(const bf16x4*)&t[base + ((size_t)hh * 64 + (w + 1)) * FCH + f0];
#pragma unroll
                for (int e = 0; e < 4; e++) cn[rr][e] = bf2f(v[e]);
            }
        }
        bf16x4 ov;
#pragma unroll
        for (int e = 0; e < 4; e++) {
            float acc = bias4[e];
#pragma unroll
            for (int rr = 0; rr < 3; rr++) {
                acc += wt[rr * 3 + 0][e] * cm1[rr][e];
                acc += wt[rr * 3 + 1][e] * cc[rr][e];
                acc += wt[rr * 3 + 2][e] * cn[rr][e];
            }
            ov[e] = f2bf(0.5f * acc * (1.f + erff(acc * 0.70710678118654752f)));
        }
        *(bf16x4*)&t2[base + ((size_t)h * 64 + w) * FCH + f0] = ov;
#pragma unroll
        for (int rr = 0; rr < 3; rr++)
#pragma unroll
            for (int e = 0; e < 4; e++) { cm1[rr][e] = cc[rr][e]; cc[rr][e] = cn[rr][e]; }
    }
}

extern "C" void kernel_launch(void* const* d_in, const int* in_sizes, int n_in,
                              void* d_out, int out_size, void* d_ws, size_t ws_size,
                              hipStream_t stream)
{
    (void)in_sizes; (void)n_in; (void)ws_size; (void)out_size;
    const float* x      = (const float*)d_in[0];
    const int*   ridx   = (const int*)d_in[1];
    const float* n1g    = (const float*)d_in[4];
    const float* n1b    = (const float*)d_in[5];
    const float* in_w   = (const float*)d_in[6];
    const float* conv_w = (const float*)d_in[7];
    const float* conv_b = (const float*)d_in[8];
    const float* xp_w   = (const float*)d_in[9];
    const float* dt_w   = (const float*)d_in[10];
    const float* dt_b   = (const float*)d_in[11];
    const float* A_log  = (const float*)d_in[12];
    const float* Dp     = (const float*)d_in[13];
    const float* out_w  = (const float*)d_in[14];
    const float* n2g    = (const float*)d_in[15];
    const float* n2b    = (const float*)d_in[16];
    const float* gate_w = (const float*)d_in[17];
    const float* fc1_w  = (const float*)d_in[18];
    const float* fc1_b  = (const float*)d_in[19];
    const float* pe_w   = (const float*)d_in[20];
    const float* pe_b   = (const float*)d_in[21];
    const float* fc2_w  = (const float*)d_in[22];
    const float* fc2_b  = (const float*)d_in[23];
    float* out = (float*)d_out;

    float* ws = (float*)d_ws;
    short* wb   = (short*)ws;                       // [0, 215040)
    float* regA = ws + 215040;                      // xn(bf16) -> I(f32) -> tbuf(bf16)   [2,097,152]
    float* regB = regA + 2097152;                   // hg(bf16, 8192x768) -> {y6,x1,xn2,t2} [9,437,184]
    float* regC = regB + 9437184;                   // ub(bf16)                           [4,718,592]
    float* regD = regC + 4718592;                   // ymix(bf16)                         [4,718,592]
    float* regE = regD + 4718592;                   // dtb(bf16)                          [4,718,592]
    float* regF = regE + 4718592;                   // PS (f32 pairs)                     [2,359,296]
    float* regG = regF + 2359296;                   // xpbc (f32)                         [196,608]
    float* smallb = regG + 196608;

    short* xn   = (short*)regA;
    float* Ibuf = regA;
    short* tbuf = (short*)regA;
    short* hg   = (short*)regB;                     // 8192*768 bf16 = 3,145,728 shorts
    float* y6   = regB;
    float* x1   = regB + 3145728;
    short* xn2  = (short*)(regB + 4194304);
    short* t2   = (short*)(regB + 4718592);
    short* ub   = (short*)regC;
    short* ymix = (short*)regD;
    short* dtb  = (short*)regE;
    float* PS   = regF;
    float* xpbc = regG;
    float* means = smallb;
    float* gbuf  = smallb + 768;
    int*   invb  = (int*)(gbuf + 8);

    const int M6 = SBN * LLEN;   // 24576
    const int M2 = NB * LLEN;    // 8192

    conv_comp<<<NCBLK + 576, 256, 0, stream>>>(in_w, xp_w, dt_w, out_w, fc1_w, fc2_w, wb);
    hipMemsetAsync(means, 0, 768 * sizeof(float), stream);
    // LN1 on fwd rows only (rev/shf are row permutations of fwd through the linear ops)
    prep_ln1<<<M2 / 4, 256, 0, stream>>>(x, n1g, n1b, xn);
    // fused in_proj: [h | gate] N=768, bf16 out, M=8192
    gemm_w<5><<<dim3(M2 / 64, 6), 256, 0, stream>>>(xn, CCH, wb + OFF_IN, CCH, 768, nullptr, nullptr, 0, nullptr, hg, 768, nullptr, CCH);
    // depthwise conv with per-direction row gather
    dwconv_silu_v3<<<768, 192, 0, stream>>>(hg, ridx, conv_w, conv_b, ub);
    // merged dt(softplus, bf16) + B/C(f32) projection: N=392
    gemm_w<7><<<dim3(M6 / 64, 4), 256, 0, stream>>>(ub, DI, wb + OFF_DTC, DI, 392, dt_b, nullptr, 0, nullptr, dtb, DI, xpbc, DI);
    // selective scan (3 kernels; launch boundaries are the grid barriers)
    scan_phaseA2<<<SBN * NCHUNK, DI, 0, stream>>>(dtb, xpbc, ub, A_log, PS);
    scan_phaseB2<<<36, 256, 0, stream>>>(PS, Ibuf);
    scan_phaseC2<<<SBN * NCHUNK, DI, 0, stream>>>(dtb, xpbc, ub, hg, ridx, A_log, Dp, Ibuf, ymix);
    // out_proj + fused column sums
    gemm_w<8><<<dim3(M6 / 64, 1), 256, 0, stream>>>(ymix, DI, wb + OFF_OUT, DI, CCH, nullptr, nullptr, 0, y6, nullptr, CCH, means, DI);
    gate_inv<<<17, 384, 0, stream>>>(means, gate_w, gbuf, ridx, invb);
    combine_ln2<<<M2 / 4, 256, 0, stream>>>(x, y6, gbuf, invb, n2g, n2b, x1, xn2);
    // MixFFN
    gemm_w<6><<<dim3(M2 / 64, 4), 256, 0, stream>>>(xn2, CCH, wb + OFF_FC1, CCH, FCH, fc1_b, nullptr, 0, nullptr, tbuf, FCH, nullptr, CCH);
    peconv_gelu_v2<<<256, 256, 0, stream>>>(tbuf, pe_w, pe_b, t2);
    gemm_w<3><<<dim3(M2 / 64, 1), 256, 0, stream>>>(t2, FCH, wb + OFF_FC2, FCH, CCH, fc2_b, x1, CCH, out, nullptr, CCH, nullptr, FCH);
}